// Round 1
// baseline (5329.329 us; speedup 1.0000x reference)
//
#include <hip/hip_runtime.h>
#include <math.h>

#define N_NODES 100000
#define N_EDGES 3200000

__device__ __forceinline__ float gelu_tanh(float x) {
    // jax.nn.gelu default approximate=True (tanh form)
    const float c = 0.7978845608028654f;  // sqrt(2/pi)
    float t = tanhf(c * (x + 0.044715f * x * x * x));
    return 0.5f * x * (1.0f + t);
}

// Distinguish int64 vs int32 edge_index layout: under little-endian int64 with
// values in [0, 1e5), every odd dword is 0. Under int32 these are random src
// values; P(all 64 == 0) ~ (1e-5)^64 ~ 0.
__global__ void detect_kernel(const unsigned int* __restrict__ ei, int* __restrict__ flag) {
    unsigned int v = ei[2 * threadIdx.x + 1];
    unsigned long long m = __ballot(v != 0u);
    if (threadIdx.x == 0) flag[0] = (m != 0ull) ? 1 : 0;  // 1 => int32 layout
}

// Decode edge_index into int32 src/dst arrays and accumulate in-degree (dst).
__global__ void decode_deg_kernel(const void* __restrict__ ei, const int* __restrict__ flag,
                                  int* __restrict__ sbuf, int* __restrict__ dbuf,
                                  float* __restrict__ deg) {
    int e = blockIdx.x * blockDim.x + threadIdx.x;
    if (e >= N_EDGES) return;
    int s, d;
    if (flag[0]) {
        const int* p = (const int*)ei;
        s = p[e];
        d = p[N_EDGES + e];
    } else {
        const long long* p = (const long long*)ei;
        s = (int)p[e];
        d = (int)p[N_EDGES + e];
    }
    sbuf[e] = s;
    dbuf[e] = d;
    atomicAdd(&deg[d], 1.0f);
}

// deg -> dinv in place; +1 accounts for the self-loop the reference appends.
__global__ void dinv_kernel(float* __restrict__ deg) {
    int n = blockIdx.x * blockDim.x + threadIdx.x;
    if (n < N_NODES) deg[n] = rsqrtf(deg[n] + 1.0f);
}

// Layer 1 pre-propagation: h2[n] = dinv[n] * (X[n] @ W1), padded to stride 12.
__global__ void node1_kernel(const float* __restrict__ X, const float* __restrict__ W,
                             const float* __restrict__ dinv, float* __restrict__ h2) {
    int n = blockIdx.x * blockDim.x + threadIdx.x;
    if (n >= N_NODES) return;
    float x[11];
#pragma unroll
    for (int i = 0; i < 11; i++) x[i] = X[n * 11 + i];
    float di = dinv[n];
#pragma unroll
    for (int j = 0; j < 11; j++) {
        float a = 0.0f;
#pragma unroll
        for (int i = 0; i < 11; i++) a += x[i] * W[i * 11 + j];
        h2[n * 12 + j] = di * a;
    }
    h2[n * 12 + 11] = 0.0f;
}

// Edge propagation: acc[dst] += h2[src]  (dinv[dst] applied at finalize).
template <int F>
__global__ void edge_kernel(const int* __restrict__ sbuf, const int* __restrict__ dbuf,
                            const float* __restrict__ h2, float* __restrict__ acc) {
    int e = blockIdx.x * blockDim.x + threadIdx.x;
    if (e >= N_EDGES) return;
    int s = sbuf[e];
    int d = dbuf[e];
    const float4* hp = (const float4*)(h2 + (size_t)s * 12);
    float4 v0 = hp[0];
    float4 v1 = hp[1];
    float4 v2 = hp[2];
    float* ap = acc + (size_t)d * 12;
    atomicAdd(ap + 0, v0.x);
    atomicAdd(ap + 1, v0.y);
    atomicAdd(ap + 2, v0.z);
    atomicAdd(ap + 3, v0.w);
    atomicAdd(ap + 4, v1.x);
    atomicAdd(ap + 5, v1.y);
    atomicAdd(ap + 6, v1.z);
    atomicAdd(ap + 7, v1.w);
    atomicAdd(ap + 8, v2.x);
    atomicAdd(ap + 9, v2.y);
    if (F == 11) atomicAdd(ap + 10, v2.z);
}

// Fused: finalize layer L (add self-loop term, scale by dinv[dst], +bias, gelu)
// then compute next layer's pre-propagation h2out = dinv * (t @ W).
template <int OUT>
__global__ void nodemid_kernel(const float* __restrict__ acc, const float* __restrict__ h2in,
                               const float* __restrict__ bias, const float* __restrict__ W,
                               const float* __restrict__ dinv, float* __restrict__ h2out) {
    int n = blockIdx.x * blockDim.x + threadIdx.x;
    if (n >= N_NODES) return;
    float di = dinv[n];
    float t[11];
#pragma unroll
    for (int i = 0; i < 11; i++) {
        float v = di * (acc[n * 12 + i] + h2in[n * 12 + i]) + bias[i];
        t[i] = gelu_tanh(v);
    }
#pragma unroll
    for (int j = 0; j < OUT; j++) {
        float a = 0.0f;
#pragma unroll
        for (int i = 0; i < 11; i++) a += t[i] * W[i * OUT + j];
        h2out[n * 12 + j] = di * a;
    }
#pragma unroll
    for (int j = OUT; j < 12; j++) h2out[n * 12 + j] = 0.0f;
}

// Final layer: finalize + log_softmax over 10 classes.
__global__ void out_kernel(const float* __restrict__ acc, const float* __restrict__ h2in,
                           const float* __restrict__ bias, const float* __restrict__ dinv,
                           float* __restrict__ out) {
    int n = blockIdx.x * blockDim.x + threadIdx.x;
    if (n >= N_NODES) return;
    float di = dinv[n];
    float t[10];
    float m = -1e30f;
#pragma unroll
    for (int j = 0; j < 10; j++) {
        t[j] = di * (acc[n * 12 + j] + h2in[n * 12 + j]) + bias[j];
        m = fmaxf(m, t[j]);
    }
    float s = 0.0f;
#pragma unroll
    for (int j = 0; j < 10; j++) s += expf(t[j] - m);
    float ls = logf(s);
#pragma unroll
    for (int j = 0; j < 10; j++) out[n * 10 + j] = t[j] - m - ls;
}

extern "C" void kernel_launch(void* const* d_in, const int* in_sizes, int n_in,
                              void* d_out, int out_size, void* d_ws, size_t ws_size,
                              hipStream_t stream) {
    const float* X  = (const float*)d_in[0];
    const void*  ei = d_in[1];
    const float* W1 = (const float*)d_in[2];
    const float* b1 = (const float*)d_in[3];
    const float* W2 = (const float*)d_in[4];
    const float* b2 = (const float*)d_in[5];
    const float* W3 = (const float*)d_in[6];
    const float* b3 = (const float*)d_in[7];
    float* out = (float*)d_out;

    const size_t N = N_NODES;
    const size_t E = N_EDGES;
    float* ws   = (float*)d_ws;
    float* deg  = ws;                 // [N]      (becomes dinv in place)
    float* acc1 = ws + N;             // [12N]
    float* acc2 = acc1 + 12 * N;      // [12N]
    float* acc3 = acc2 + 12 * N;      // [12N]
    float* h2a  = acc3 + 12 * N;      // [12N]
    float* h2b  = h2a + 12 * N;       // [12N]
    int*   sbuf = (int*)(h2b + 12 * N);  // [E]
    int*   dbuf = sbuf + E;              // [E]
    int*   flag = dbuf + E;              // [1]

    // Zero deg + acc1..acc3 (contiguous region of 37N floats).
    hipMemsetAsync(deg, 0, 37 * N * sizeof(float), stream);

    detect_kernel<<<1, 64, 0, stream>>>((const unsigned int*)ei, flag);

    const int eb = (N_EDGES + 255) / 256;
    const int nb = (N_NODES + 255) / 256;

    decode_deg_kernel<<<eb, 256, 0, stream>>>(ei, flag, sbuf, dbuf, deg);
    dinv_kernel<<<nb, 256, 0, stream>>>(deg);

    node1_kernel<<<nb, 256, 0, stream>>>(X, W1, deg, h2a);
    edge_kernel<11><<<eb, 256, 0, stream>>>(sbuf, dbuf, h2a, acc1);
    nodemid_kernel<11><<<nb, 256, 0, stream>>>(acc1, h2a, b1, W2, deg, h2b);
    edge_kernel<11><<<eb, 256, 0, stream>>>(sbuf, dbuf, h2b, acc2);
    nodemid_kernel<10><<<nb, 256, 0, stream>>>(acc2, h2b, b2, W3, deg, h2a);
    edge_kernel<10><<<eb, 256, 0, stream>>>(sbuf, dbuf, h2a, acc3);
    out_kernel<<<nb, 256, 0, stream>>>(acc3, h2a, b3, deg, out);
}

// Round 2
// 818.040 us; speedup vs baseline: 6.5148x; 6.5148x over previous
//
#include <hip/hip_runtime.h>
#include <math.h>

#define N_NODES 100000
#define N_EDGES 3200000

__device__ __forceinline__ float gelu_tanh(float x) {
    // jax.nn.gelu default approximate=True (tanh form)
    const float c = 0.7978845608028654f;  // sqrt(2/pi)
    float t = tanhf(c * (x + 0.044715f * x * x * x));
    return 0.5f * x * (1.0f + t);
}

// Distinguish int64 vs int32 edge_index layout: under little-endian int64 with
// values in [0, 1e5), every odd dword is 0. Under int32 these are random src
// values; P(all 64 == 0) ~ 0.
__global__ void detect_kernel(const unsigned int* __restrict__ ei, int* __restrict__ flag) {
    unsigned int v = ei[2 * threadIdx.x + 1];
    unsigned long long m = __ballot(v != 0u);
    if (threadIdx.x == 0) flag[0] = (m != 0ull) ? 1 : 0;  // 1 => int32 layout
}

__device__ __forceinline__ int load_idx(const void* ei, int f, size_t pos) {
    if (f) return ((const int*)ei)[pos];
    return (int)((const long long*)ei)[pos];
}

// Histogram of in-degrees (dst half of edge_index).
__global__ void hist_kernel(const void* __restrict__ ei, const int* __restrict__ flag,
                            int* __restrict__ cnt) {
    int e = blockIdx.x * blockDim.x + threadIdx.x;
    if (e >= N_EDGES) return;
    int d = load_idx(ei, flag[0], (size_t)N_EDGES + e);
    atomicAdd(&cnt[d], 1);
}

// Single-block exclusive scan of cnt[N] -> off[N+1]; also copies into cur[N].
__global__ void scan_kernel(const int* __restrict__ cnt, int* __restrict__ off,
                            int* __restrict__ cur) {
    __shared__ int sums[1024];
    const int CH = (N_NODES + 1023) / 1024;  // 98
    int t = threadIdx.x;
    int base = t * CH;
    int s = 0;
    for (int i = 0; i < CH; i++) {
        int idx = base + i;
        if (idx < N_NODES) s += cnt[idx];
    }
    sums[t] = s;
    __syncthreads();
    int val = s;
    for (int o = 1; o < 1024; o <<= 1) {
        int add = (t >= o) ? sums[t - o] : 0;
        __syncthreads();
        val += add;
        sums[t] = val;
        __syncthreads();
    }
    int excl = val - s;
    for (int i = 0; i < CH; i++) {
        int idx = base + i;
        if (idx < N_NODES) {
            off[idx] = excl;
            cur[idx] = excl;
            excl += cnt[idx];
        }
    }
    if (t == 1023) off[N_NODES] = excl;  // == N_EDGES
}

// dinv[n] = rsqrt(indeg + 1)   (+1 = the appended self-loop)
__global__ void dinv_kernel(const int* __restrict__ cnt, float* __restrict__ dinv) {
    int n = blockIdx.x * blockDim.x + threadIdx.x;
    if (n < N_NODES) dinv[n] = rsqrtf((float)cnt[n] + 1.0f);
}

// Scatter src ids into CSR order by dst.
__global__ void scatter_kernel(const void* __restrict__ ei, const int* __restrict__ flag,
                               int* __restrict__ cur, int* __restrict__ csr) {
    int e = blockIdx.x * blockDim.x + threadIdx.x;
    if (e >= N_EDGES) return;
    int f = flag[0];
    int s = load_idx(ei, f, e);
    int d = load_idx(ei, f, (size_t)N_EDGES + e);
    int pos = atomicAdd(&cur[d], 1);
    csr[pos] = s;
}

// Layer 1 pre-propagation: h2[n] = dinv[n] * (X[n] @ W1), padded to stride 12.
__global__ void node1_kernel(const float* __restrict__ X, const float* __restrict__ W,
                             const float* __restrict__ dinv, float* __restrict__ h2) {
    int n = blockIdx.x * blockDim.x + threadIdx.x;
    if (n >= N_NODES) return;
    float x[11];
#pragma unroll
    for (int i = 0; i < 11; i++) x[i] = X[n * 11 + i];
    float di = dinv[n];
#pragma unroll
    for (int j = 0; j < 11; j++) {
        float a = 0.0f;
#pragma unroll
        for (int i = 0; i < 11; i++) a += x[i] * W[i * 11 + j];
        h2[n * 12 + j] = di * a;
    }
    h2[n * 12 + 11] = 0.0f;
}

// Fused gather + finalize + gelu + next-layer GEMM. 4 lanes per node.
template <int OUT>
__global__ void mid_kernel(const int* __restrict__ off, const int* __restrict__ csr,
                           const float* __restrict__ h2in, const float* __restrict__ bias,
                           const float* __restrict__ W, const float* __restrict__ dinv,
                           float* __restrict__ h2out) {
    int tid = blockIdx.x * blockDim.x + threadIdx.x;
    int n = tid >> 2;
    int p = tid & 3;
    if (n >= N_NODES) return;
    int lo = off[n], hi = off[n + 1];
    float a[11];
    if (p == 0) {  // self-loop term
        const float4* sp = (const float4*)(h2in + (size_t)n * 12);
        float4 u0 = sp[0], u1 = sp[1], u2 = sp[2];
        a[0] = u0.x; a[1] = u0.y; a[2] = u0.z; a[3] = u0.w;
        a[4] = u1.x; a[5] = u1.y; a[6] = u1.z; a[7] = u1.w;
        a[8] = u2.x; a[9] = u2.y; a[10] = u2.z;
    } else {
#pragma unroll
        for (int i = 0; i < 11; i++) a[i] = 0.0f;
    }
    for (int e = lo + p; e < hi; e += 4) {
        int s = csr[e];
        const float4* hp = (const float4*)(h2in + (size_t)s * 12);
        float4 v0 = hp[0], v1 = hp[1], v2 = hp[2];
        a[0] += v0.x; a[1] += v0.y; a[2] += v0.z; a[3] += v0.w;
        a[4] += v1.x; a[5] += v1.y; a[6] += v1.z; a[7] += v1.w;
        a[8] += v2.x; a[9] += v2.y; a[10] += v2.z;
    }
#pragma unroll
    for (int i = 0; i < 11; i++) {
        a[i] += __shfl_xor(a[i], 1);
        a[i] += __shfl_xor(a[i], 2);
    }
    float di = dinv[n];
    float t[11];
#pragma unroll
    for (int i = 0; i < 11; i++) t[i] = gelu_tanh(di * a[i] + bias[i]);
#pragma unroll
    for (int j0 = 0; j0 < 3; j0++) {
        int j = p + 4 * j0;
        if (j >= 12) continue;
        float o = 0.0f;
        if (j < OUT) {
            float acc = 0.0f;
#pragma unroll
            for (int i = 0; i < 11; i++) acc += t[i] * W[i * OUT + j];
            o = di * acc;
        }
        h2out[(size_t)n * 12 + j] = o;
    }
}

// Final layer: gather + finalize + log_softmax (10 classes). 4 lanes per node.
__global__ void final_kernel(const int* __restrict__ off, const int* __restrict__ csr,
                             const float* __restrict__ h2in, const float* __restrict__ bias,
                             const float* __restrict__ dinv, float* __restrict__ out) {
    int tid = blockIdx.x * blockDim.x + threadIdx.x;
    int n = tid >> 2;
    int p = tid & 3;
    if (n >= N_NODES) return;
    int lo = off[n], hi = off[n + 1];
    float a[10];
    if (p == 0) {
        const float4* sp = (const float4*)(h2in + (size_t)n * 12);
        float4 u0 = sp[0], u1 = sp[1], u2 = sp[2];
        a[0] = u0.x; a[1] = u0.y; a[2] = u0.z; a[3] = u0.w;
        a[4] = u1.x; a[5] = u1.y; a[6] = u1.z; a[7] = u1.w;
        a[8] = u2.x; a[9] = u2.y;
    } else {
#pragma unroll
        for (int i = 0; i < 10; i++) a[i] = 0.0f;
    }
    for (int e = lo + p; e < hi; e += 4) {
        int s = csr[e];
        const float4* hp = (const float4*)(h2in + (size_t)s * 12);
        float4 v0 = hp[0], v1 = hp[1], v2 = hp[2];
        a[0] += v0.x; a[1] += v0.y; a[2] += v0.z; a[3] += v0.w;
        a[4] += v1.x; a[5] += v1.y; a[6] += v1.z; a[7] += v1.w;
        a[8] += v2.x; a[9] += v2.y;
    }
#pragma unroll
    for (int i = 0; i < 10; i++) {
        a[i] += __shfl_xor(a[i], 1);
        a[i] += __shfl_xor(a[i], 2);
    }
    float di = dinv[n];
    float t[10];
    float m = -1e30f;
#pragma unroll
    for (int j = 0; j < 10; j++) {
        t[j] = di * a[j] + bias[j];
        m = fmaxf(m, t[j]);
    }
    float s = 0.0f;
#pragma unroll
    for (int j = 0; j < 10; j++) s += expf(t[j] - m);
    float ls = logf(s);
    for (int j = p; j < 10; j += 4) out[(size_t)n * 10 + j] = t[j] - m - ls;
}

extern "C" void kernel_launch(void* const* d_in, const int* in_sizes, int n_in,
                              void* d_out, int out_size, void* d_ws, size_t ws_size,
                              hipStream_t stream) {
    const float* X  = (const float*)d_in[0];
    const void*  ei = d_in[1];
    const float* W1 = (const float*)d_in[2];
    const float* b1 = (const float*)d_in[3];
    const float* W2 = (const float*)d_in[4];
    const float* b2 = (const float*)d_in[5];
    const float* W3 = (const float*)d_in[6];
    const float* b3 = (const float*)d_in[7];
    float* out = (float*)d_out;

    const size_t N = N_NODES;
    const size_t E = N_EDGES;
    // Workspace layout (dword-aligned so h2a is 16B-aligned: keep every region
    // a multiple of 4 dwords; off gets N+4).
    int*   cnt  = (int*)d_ws;           // [N]
    int*   off  = cnt + N;              // [N+4] (uses N+1)
    int*   cur  = off + N + 4;          // [N]
    int*   csr  = cur + N;              // [E]
    float* dinv = (float*)(csr + E);    // [N]
    float* h2a  = dinv + N;             // [12N]  (offset dwords: 4N+4+E+N ≡ 0 mod 4)
    float* h2b  = h2a + 12 * N;         // [12N]
    int*   flag = (int*)(h2b + 12 * N); // [1]

    hipMemsetAsync(cnt, 0, N * sizeof(int), stream);

    const int eb = (N_EDGES + 255) / 256;
    const int nb = (N_NODES + 255) / 256;
    const int gb = (4 * N_NODES + 255) / 256;

    detect_kernel<<<1, 64, 0, stream>>>((const unsigned int*)ei, flag);
    hist_kernel<<<eb, 256, 0, stream>>>(ei, flag, cnt);
    scan_kernel<<<1, 1024, 0, stream>>>(cnt, off, cur);
    dinv_kernel<<<nb, 256, 0, stream>>>(cnt, dinv);
    scatter_kernel<<<eb, 256, 0, stream>>>(ei, flag, cur, csr);

    node1_kernel<<<nb, 256, 0, stream>>>(X, W1, dinv, h2a);
    mid_kernel<11><<<gb, 256, 0, stream>>>(off, csr, h2a, b1, W2, dinv, h2b);
    mid_kernel<10><<<gb, 256, 0, stream>>>(off, csr, h2b, b2, W3, dinv, h2a);
    final_kernel<<<gb, 256, 0, stream>>>(off, csr, h2a, b3, dinv, out);
}